// Round 8
// baseline (684.941 us; speedup 1.0000x reference)
//
#include <hip/hip_runtime.h>

// Segment-sum via LDS bucket sort + direct LDS-accumulate reduce.
// R11 (3rd resubmit; three consecutive GPU-acquisition timeouts, never
// measured): R8/R9/R10 all measured ~352-354us despite structurally
// different sort pipelines; every individual dispatch <118us. Conclusion:
// cost is spread across many medium dispatches (CSR build + reduce re-read
// + serialized single-block scan). This round deletes the CSR stage and the
// standalone reduce: after bucket-grouping, one block per bucket streams
// its (row,id) records and accumulates w[id][0..63] directly into an LDS
// acc tile via ds_add_f32 (one coalesced 256B wave-load + one conflict-free
// LDS atomic per record), two 128-row half-passes to fit 32KB static LDS.
// scan_flat (single-block, serialized) replaced by R8's 2-dispatch scan.
// Constraints: N <= 65536 (bucket = row>>8, <=256 buckets); within-row
// order arbitrary (segment-sum order-insensitive; absmax tol 0.0625).

#define CEDGE 4096        // edges per block in bucket_hist / bucket_scatter
#define WROWS 256         // rows per bucket
#define SHIFT 8
#define TILE 1024         // scan tile: 256 threads x 4 elems

__global__ __launch_bounds__(256) void bucket_hist(
    const int* __restrict__ edge0, int* __restrict__ cnt,
    int E, int nblk, int NB)
{
    __shared__ int lh[256];
    int t = threadIdx.x, blk = blockIdx.x;
    lh[t] = 0;
    __syncthreads();
    #pragma unroll
    for (int j = 0; j < 4; ++j) {
        int idx4 = blk * 1024 + j * 256 + t;
        int base = idx4 * 4;
        if (base + 3 < E) {
            int4 r = ((const int4*)edge0)[idx4];
            atomicAdd(&lh[r.x >> SHIFT], 1);
            atomicAdd(&lh[r.y >> SHIFT], 1);
            atomicAdd(&lh[r.z >> SHIFT], 1);
            atomicAdd(&lh[r.w >> SHIFT], 1);
        } else {
            for (int i = base; i < E && i < base + 4; ++i)
                atomicAdd(&lh[edge0[i] >> SHIFT], 1);
        }
    }
    __syncthreads();
    if (t < NB) cnt[t * nblk + blk] = lh[t];
}

// R8-style 2-dispatch parallel scan over M elements (M=NB*nblk=38416 -> 38
// tiles; scan_final's redundant tile-scan requires numTiles <= 64).
__global__ __launch_bounds__(256) void scan_partial(
    const int* __restrict__ a, int* __restrict__ tileSum, int M)
{
    __shared__ int wsum[4];
    int t = threadIdx.x;
    int base = blockIdx.x * TILE + t * 4;
    int s = 0;
    #pragma unroll
    for (int k = 0; k < 4; ++k) {
        int i = base + k;
        if (i < M) s += a[i];
    }
    for (int off = 1; off < 64; off <<= 1) s += __shfl_xor(s, off);
    if ((t & 63) == 0) wsum[t >> 6] = s;
    __syncthreads();
    if (t == 0) tileSum[blockIdx.x] = wsum[0] + wsum[1] + wsum[2] + wsum[3];
}

__global__ __launch_bounds__(256) void scan_final(
    const int* __restrict__ a, const int* __restrict__ tileSum,
    int* __restrict__ ax, int M, int numTiles)
{
    __shared__ int wtot[4];
    __shared__ int tilePre;
    int t = threadIdx.x;
    int lane = t & 63, wv = t >> 6;

    if (t < 64) {                            // wave 0: scan tile sums
        int v0 = (t < numTiles) ? tileSum[t] : 0;
        int v = v0;
        #pragma unroll
        for (int off = 1; off < 64; off <<= 1) {
            int u = __shfl_up(v, off);
            if (t >= off) v += u;
        }
        if (t == blockIdx.x) tilePre = v - v0;   // exclusive prefix of this tile
    }

    int base = blockIdx.x * TILE + t * 4;
    int c[4]; int s = 0;
    #pragma unroll
    for (int k = 0; k < 4; ++k) {
        int i = base + k;
        c[k] = (i < M) ? a[i] : 0;
        s += c[k];
    }
    int inc = s;
    #pragma unroll
    for (int off = 1; off < 64; off <<= 1) {
        int u = __shfl_up(inc, off);
        if (lane >= off) inc += u;
    }
    if (lane == 63) wtot[wv] = inc;
    __syncthreads();
    int wpre = 0;
    for (int w = 0; w < wv; ++w) wpre += wtot[w];
    int pre = tilePre + wpre + (inc - s);
    #pragma unroll
    for (int k = 0; k < 4; ++k) {
        int i = base + k;
        if (i < M) ax[i] = pre;
        pre += c[k];
    }
}

__global__ __launch_bounds__(256) void bucket_scatter(
    const int* __restrict__ edge0, const int* __restrict__ cntX,
    int* __restrict__ recs /* int2[E] */, int E, int nblk, int NB)
{
    __shared__ int lh[256];      // per-bucket local counts
    __shared__ int so[256];      // staging offsets (exclusive scan of lh)
    __shared__ int gb[256];      // global record base per bucket, this block
    __shared__ int ws4[4];
    __shared__ int2 stage[CEDGE];
    int t = threadIdx.x, lane = t & 63, wv = t >> 6, blk = blockIdx.x;
    lh[t] = 0;
    if (t < NB) gb[t] = cntX[t * nblk + blk];
    __syncthreads();

    int rowR[16], rkR[16];
    #pragma unroll
    for (int j = 0; j < 4; ++j) {
        int idx4 = blk * 1024 + j * 256 + t;
        int base = idx4 * 4;
        if (base + 3 < E) {
            int4 r = ((const int4*)edge0)[idx4];
            rowR[j*4+0] = r.x; rkR[j*4+0] = atomicAdd(&lh[r.x >> SHIFT], 1);
            rowR[j*4+1] = r.y; rkR[j*4+1] = atomicAdd(&lh[r.y >> SHIFT], 1);
            rowR[j*4+2] = r.z; rkR[j*4+2] = atomicAdd(&lh[r.z >> SHIFT], 1);
            rowR[j*4+3] = r.w; rkR[j*4+3] = atomicAdd(&lh[r.w >> SHIFT], 1);
        } else {
            #pragma unroll
            for (int c = 0; c < 4; ++c) {
                int i = base + c;
                if (i < E) {
                    int rr = edge0[i];
                    rowR[j*4+c] = rr;
                    rkR[j*4+c]  = atomicAdd(&lh[rr >> SHIFT], 1);
                } else {
                    rowR[j*4+c] = -1;
                    rkR[j*4+c]  = 0;
                }
            }
        }
    }
    __syncthreads();
    // exclusive scan of lh (256 entries) -> so
    {
        int v = lh[t];
        int inc = v;
        #pragma unroll
        for (int off = 1; off < 64; off <<= 1) {
            int u = __shfl_up(inc, off);
            if (lane >= off) inc += u;
        }
        if (lane == 63) ws4[wv] = inc;
        __syncthreads();
        int wpre = 0;
        for (int w = 0; w < wv; ++w) wpre += ws4[w];
        so[t] = wpre + inc - v;
    }
    __syncthreads();
    // place records bucket-sorted into LDS staging
    #pragma unroll
    for (int k = 0; k < 16; ++k) {
        int row = rowR[k];
        if (row >= 0) {
            int b = row >> SHIFT;
            int id = blk * CEDGE + ((k >> 2) * 256 + t) * 4 + (k & 3);
            stage[so[b] + rkR[k]] = make_int2(row, id);
        }
    }
    __syncthreads();
    // linear LDS read -> contiguous-run global writes
    int Ctot = E - blk * CEDGE; if (Ctot > CEDGE) Ctot = CEDGE;
    int2* rout = (int2*)recs;
    for (int p = t; p < Ctot; p += 256) {
        int2 rec = stage[p];
        int b = rec.x >> SHIFT;
        rout[gb[b] + (p - so[b])] = rec;
    }
}

// One block per bucket. Streams the bucket's records; per record, one wave
// loads w[id][lane] (64 lanes x 4B = 256B coalesced = the irreducible
// gather) and ds_add_f32's into acc[row&127][lane] (bank = lane%32,
// 2-way alias = free). Two half-passes (rows 0-127 / 128-255) keep acc at
// 32KB static LDS. Finally dump acc -> out coalesced.
__global__ __launch_bounds__(1024) void bucket_reduce(
    const int* __restrict__ cntX, const int* __restrict__ recs,
    const float* __restrict__ w, float* __restrict__ out,
    int E, int nblk, int NB, int N)
{
    __shared__ float acc[128][64];
    int t = threadIdx.x, lane = t & 63, wv = t >> 6;   // 16 waves
    int b = blockIdx.x;
    int S0 = cntX[b * nblk];
    int S1 = (b + 1 < NB) ? cntX[(b + 1) * nblk] : E;
    const int2* rin = (const int2*)recs;

    for (int half = 0; half < 2; ++half) {
        // zero acc: 8192 floats / 1024 threads = 8 each
        #pragma unroll
        for (int k = 0; k < 8; ++k) ((float*)acc)[k * 1024 + t] = 0.f;
        __syncthreads();

        // waves take disjoint 64-record batches: batch index = wv + 16*i
        for (int base = S0 + wv * 64; base < S1; base += 16 * 64) {
            int m = S1 - base; if (m > 64) m = 64;    // wave-uniform
            int2 my = (lane < m) ? rin[base + lane] : make_int2(-1, 0);
            for (int j = 0; j < m; ++j) {
                int row = __shfl(my.x, j);            // wave-uniform value
                int lr  = row & (WROWS - 1);
                if ((lr >> 7) == half) {              // uniform branch
                    int id = __shfl(my.y, j);
                    float v = w[(size_t)id * 64 + lane];
                    atomicAdd(&acc[lr & 127][lane], v);
                }
            }
        }
        __syncthreads();

        // dump this half's 128 rows, coalesced (256B per wave-row)
        int r0 = (b << SHIFT) + (half << 7);
        for (int rr = wv; rr < 128; rr += 16) {
            int gr = r0 + rr;
            if (gr < N) out[(size_t)gr * 64 + lane] = acc[rr][lane];
        }
        __syncthreads();   // protect acc from next half's re-zero
    }
}

extern "C" void kernel_launch(void* const* d_in, const int* in_sizes, int n_in,
                              void* d_out, int out_size, void* d_ws, size_t ws_size,
                              hipStream_t stream) {
    const int*   edge   = (const int*)d_in[0];     // (2,E) int32; rows = edge[0,:]
    const float* edge_w = (const float*)d_in[1];   // (E, 64) float32
    int E = in_sizes[0] / 2;
    int N = out_size / 64;
    int nblk = (E + CEDGE - 1) / CEDGE;            // 196 for E=800000
    int NB   = (N + WROWS - 1) / WROWS;            // 196 for N=50000 (<=256)
    int M    = NB * nblk;                          // 38416
    int numTiles = (M + TILE - 1) / TILE;          // 38 (must be <=64)

    // Workspace (ints): recs[2E] | cntS[M] | cntX[M] | tileSum[64]
    int* recs    = (int*)d_ws;                     // int2[E], 8B-aligned at base
    int* cntS    = recs + 2 * (size_t)E;
    int* cntX    = cntS + M;
    int* tileSum = cntX + M;

    bucket_hist   <<<nblk, 256, 0, stream>>>(edge, cntS, E, nblk, NB);
    scan_partial  <<<numTiles, 256, 0, stream>>>(cntS, tileSum, M);
    scan_final    <<<numTiles, 256, 0, stream>>>(cntS, tileSum, cntX, M, numTiles);
    bucket_scatter<<<nblk, 256, 0, stream>>>(edge, cntX, recs, E, nblk, NB);
    bucket_reduce <<<NB, 1024, 0, stream>>>(cntX, recs, edge_w, (float*)d_out,
                                            E, nblk, NB, N);
}